// Round 4
// baseline (152.222 us; speedup 1.0000x reference)
//
#include <hip/hip_runtime.h>

// Aggregation: input [32,16,16,1024] f32 NHWC, weight [32,256,9,256] f32,
// out [32,1024,16,16] f32.
//
// out[n, g*256+cw, l] = sum_q weight[n,cw,q,l] * input[n, hi, wj, c]
//   m  = 9*(cw&3) + q  (wave-uniform);  p = m>>2 ; di = p/3 ; dj = p%3
//   c  = (m&3)*256 + l ;  hi = 4g + (cw>>6) + di - 1 ; wj = ((cw>>2)&15)+dj-1
//   (0 if hi/wj out of [0,16))
//
// Round-3 lesson: the kernel was load-LATENCY bound (49 serialized loads/wave
// explained identical 49.5us across two very different kernels). This version
// maximizes memory-level parallelism:
//   - all 9 weight float4 loads issued as one batch up front
//   - per g, all 9 gathers are UNCONDITIONAL (OOB addresses clamped into the
//     image — wave-uniform predicates) and issued in a load-only phase
//   - validity applied afterwards as a {0,1} multiplier on the weight
// Target: HBM floor ~140 MB -> ~22-25 us.

__global__ __launch_bounds__(256)
void Aggregation_33320356282418_kernel(const float* __restrict__ input,
                                       const float* __restrict__ weight,
                                       float* __restrict__ out) {
    // XCD-aware swizzle: XCD x gets contiguous block range (4 consecutive n)
    const int b   = blockIdx.x;             // 0..2047
    const int blk = (b & 7) * 256 + (b >> 3);

    const int cb  = blk & 63;               // cw-block 0..63
    const int n   = blk >> 6;               // 0..31
    const int tid = threadIdx.x;
    const int cwi = tid >> 6;               // wave id 0..3
    const int t   = tid & 63;               // lane
    const int cw  = cb * 4 + cwi;

    const int hbase = cw >> 6;              // 0..3
    const int w0    = (cw >> 2) & 15;       // 0..15
    const int mb    = 9 * (cw & 3);

    const float4* __restrict__ inp4 =
        (const float4*)(input + (size_t)n * (16 * 16 * 1024));
    const float4* __restrict__ w4 =
        (const float4*)(weight + ((size_t)(n * 256 + cw) * 9) * 256);
    float4* __restrict__ o4 =
        (float4*)(out + ((size_t)n * 1024 + cw) * 256);

    // ---- phase 0: all 9 weight loads, one batch ----
    float4 wgt[9];
#pragma unroll
    for (int q = 0; q < 9; ++q) wgt[q] = w4[q * 64 + t];

    // ---- per-q wave-uniform geometry (clamped addresses) ----
    int  base_q[9];   // float4-unit offset for clamped (row-part, col, chunk)
    int  hoff_q[9];   // hbase + di - 1
    bool wok_q[9];
#pragma unroll
    for (int q = 0; q < 9; ++q) {
        const int m  = mb + q;
        const int p  = m >> 2;              // 0..8
        const int di = p / 3;
        const int dj = p - 3 * di;
        const int wj = w0 + dj - 1;
        wok_q[q] = (unsigned)wj < 16u;
        const int wjc = min(max(wj, 0), 15);
        hoff_q[q] = hbase + di - 1;
        base_q[q] = wjc * 256 + (m & 3) * 64 + t;
    }

#pragma unroll
    for (int g = 0; g < 4; ++g) {
        // ---- phase A: 9 unconditional gathers (full MLP batch) ----
        float4 v[9];
#pragma unroll
        for (int q = 0; q < 9; ++q) {
            const int hi  = 4 * g + hoff_q[q];
            const int hic = min(max(hi, 0), 15);
            v[q] = inp4[hic * (16 * 256) + base_q[q]];
        }
        // ---- phase B: masked FMAs ----
        float4 acc = make_float4(0.f, 0.f, 0.f, 0.f);
#pragma unroll
        for (int q = 0; q < 9; ++q) {
            const int  hi = 4 * g + hoff_q[q];
            const bool ok = wok_q[q] && ((unsigned)hi < 16u);
            const float s = ok ? 1.0f : 0.0f;
            acc.x = fmaf(wgt[q].x * s, v[q].x, acc.x);
            acc.y = fmaf(wgt[q].y * s, v[q].y, acc.y);
            acc.z = fmaf(wgt[q].z * s, v[q].z, acc.z);
            acc.w = fmaf(wgt[q].w * s, v[q].w, acc.w);
        }
        o4[g * (256 * 256 / 4) + t] = acc;      // C = g*256 + cw
    }
}

extern "C" void kernel_launch(void* const* d_in, const int* in_sizes, int n_in,
                              void* d_out, int out_size, void* d_ws, size_t ws_size,
                              hipStream_t stream) {
    const float* input  = (const float*)d_in[0];   // [32,16,16,1024]
    const float* weight = (const float*)d_in[1];   // [32,256,9,256]
    float* out = (float*)d_out;                    // [32,1024,16,16]

    dim3 grid(32 * 64);    // (n, cw-block-of-4)
    dim3 block(256);       // 4 waves: one cw each
    hipLaunchKernelGGL(Aggregation_33320356282418_kernel, grid, block, 0, stream,
                       input, weight, out);
}